// Round 4
// baseline (170.308 us; speedup 1.0000x reference)
//
#include <hip/hip_runtime.h>
#include <stdint.h>

// Problem constants (GPT-2 attention block)
#define S_LEN  2048
#define EMBD   1024
#define NHEAD  16
#define HDIM   64
#define BATCHN 2
#define ROWS   (BATCHN * S_LEN)   // 4096 = flattened B*S

using bf16x8 = __attribute__((ext_vector_type(8))) __bf16;
using f32x4  = __attribute__((ext_vector_type(4))) float;

typedef const __attribute__((address_space(1))) void* gas_ptr;
typedef __attribute__((address_space(3)))       void* las_ptr;

// Async global->LDS, 16B per lane. LDS dest = wave-uniform base + lane*16.
__device__ __forceinline__ void load_lds16(const void* g, void* l) {
    __builtin_amdgcn_global_load_lds((gas_ptr)(uintptr_t)g, (las_ptr)(uintptr_t)l, 16, 0, 0);
}

// fp32 -> bf16 round-to-nearest-even
__device__ __forceinline__ unsigned short f2bf(float f) {
    unsigned u = __builtin_bit_cast(unsigned, f);
    u += 0x7fffu + ((u >> 16) & 1u);
    return (unsigned short)(u >> 16);
}

// pack 2 floats -> 1 dword of 2 bf16 (lo = a, hi = b); hw cvt_pk (no builtin)
__device__ __forceinline__ unsigned pkbf(float a, float b) {
    unsigned r;
    asm("v_cvt_pk_bf16_f32 %0, %1, %2" : "=v"(r) : "v"(a), "v"(b));
    return r;
}

// XOR-swizzled element offset within a [64][64] bf16 tile (16B-chunk XOR row&7)
__device__ __forceinline__ int swz(int row, int ebase) {
    int byte = (row << 7) + (ebase << 1);
    byte ^= (row & 7) << 4;
    return byte >> 1;
}

__global__ void cvt_f32_bf16(const float* __restrict__ src,
                             unsigned short* __restrict__ dst, int n) {
    int i = blockIdx.x * blockDim.x + threadIdx.x;
    int stride = gridDim.x * blockDim.x;
    for (int idx = i * 4; idx < n; idx += stride * 4) {
        float4 f = *(const float4*)(src + idx);
        uint2 p;
        p.x = (unsigned)f2bf(f.x) | ((unsigned)f2bf(f.y) << 16);
        p.y = (unsigned)f2bf(f.z) | ((unsigned)f2bf(f.w) << 16);
        *(uint2*)(dst + idx) = p;
    }
}

// ---------------------------------------------------------------------------
// bf16 GEMM, C[m][n] = sum_k A[m][k]*B[n][k] (+bias[n]).  A:[M][K] B:[N][K]
// 128x128 tile, BK=64, 4 waves (2x2), each wave 64x64 via 16x16x32 MFMA.
// MODE 0: write fp32 C[m*N+n] (+bias)                 (output projection)
// MODE 1: scatter bf16 q(pre-scaled)/k [B,H,S,D], V^T [B,H,D,S]  (QKV)
// ---------------------------------------------------------------------------
#define SCALE_Q 0.18033688011112042f   // 0.125 * log2(e): softmax in exp2 domain

template <int MODE>
__global__ __launch_bounds__(256) void gemm_bt(
    const unsigned short* __restrict__ A, const unsigned short* __restrict__ B,
    const float* __restrict__ bias, float* __restrict__ Cout,
    unsigned short* __restrict__ qb, unsigned short* __restrict__ kb,
    unsigned short* __restrict__ vb, int M, int N, int K)
{
    __shared__ __align__(16) unsigned short sA[128 * 64];
    __shared__ __align__(16) unsigned short sB[128 * 64];

    const int tid  = threadIdx.x;
    const int wid  = tid >> 6;
    const int lane = tid & 63;
    const int g    = lane >> 4;       // 0..3
    const int c    = lane & 15;       // 0..15
    const int bm   = blockIdx.x * 128;
    const int bn   = blockIdx.y * 128;
    const int wm   = (wid >> 1) * 64;
    const int wn   = (wid & 1) * 64;

    f32x4 acc[4][4] = {};

    for (int k0 = 0; k0 < K; k0 += 64) {
#pragma unroll
        for (int i = 0; i < 4; ++i) {
            int eoff = i * 2048 + tid * 8;
            int row  = eoff >> 6;
            int col  = eoff & 63;
            load_lds16(A + (size_t)(bm + row) * K + k0 + col,
                       &sA[i * 2048 + wid * 512]);
            load_lds16(B + (size_t)(bn + row) * K + k0 + col,
                       &sB[i * 2048 + wid * 512]);
        }
        __syncthreads();
#pragma unroll
        for (int kk = 0; kk < 2; ++kk) {
            bf16x8 af[4], bfr[4];
#pragma unroll
            for (int i = 0; i < 4; ++i)
                af[i] = *(const bf16x8*)&sA[(wm + i * 16 + c) * 64 + kk * 32 + g * 8];
#pragma unroll
            for (int j = 0; j < 4; ++j)
                bfr[j] = *(const bf16x8*)&sB[(wn + j * 16 + c) * 64 + kk * 32 + g * 8];
#pragma unroll
            for (int i = 0; i < 4; ++i)
#pragma unroll
                for (int j = 0; j < 4; ++j)
                    acc[i][j] = __builtin_amdgcn_mfma_f32_16x16x32_bf16(
                        af[i], bfr[j], acc[i][j], 0, 0, 0);
        }
        __syncthreads();
    }

#pragma unroll
    for (int i = 0; i < 4; ++i)
#pragma unroll
        for (int j = 0; j < 4; ++j) {
            int n = bn + wn + j * 16 + c;
            float bv = bias[n];
            if (MODE == 0) {
#pragma unroll
                for (int r = 0; r < 4; ++r) {
                    int m = bm + wm + i * 16 + g * 4 + r;
                    Cout[(size_t)m * N + n] = acc[i][j][r] + bv;
                }
            } else {
                int which = n >> 10, h = (n & 1023) >> 6, d = n & 63;
                if (which < 2) {
                    unsigned short* dst = (which == 0) ? qb : kb;
                    float sc = (which == 0) ? SCALE_Q : 1.0f;
#pragma unroll
                    for (int r = 0; r < 4; ++r) {
                        int m = bm + wm + i * 16 + g * 4 + r;
                        int b = m >> 11, s = m & 2047;
                        dst[(((size_t)b * NHEAD + h) * S_LEN + s) * HDIM + d] =
                            f2bf((acc[i][j][r] + bv) * sc);
                    }
                } else {
                    // V^T [B,H,D,S]: pack 4 consecutive s into one 8B store
                    int m0 = bm + wm + i * 16 + g * 4;
                    int b = m0 >> 11, s0 = m0 & 2047;
                    uint2 p;
                    p.x = pkbf(acc[i][j][0] + bv, acc[i][j][1] + bv);
                    p.y = pkbf(acc[i][j][2] + bv, acc[i][j][3] + bv);
                    *(uint2*)&vb[(((size_t)b * NHEAD + h) * HDIM + d) * S_LEN + s0] = p;
                }
            }
        }
}

// ---------------------------------------------------------------------------
// Flash-style causal attention, swapped-QK^T (lane-local softmax rows).
// Grid: 512 flat, XCD-grouped (4 bh per XCD). Block = 256 thr (4 waves),
// block handles balanced q-tile pair (pr, 31-pr): 33 KV tiles each.
// Per wave: 16 q-rows; lane owns one q-row (q = qrow0 + (lane&15)).
// K: double-buffered swizzled LDS (global_load_lds). V^T: direct global->reg.
// P^T: packed bf16 pairs through per-wave LDS rows (stride 36 dwords).
// ---------------------------------------------------------------------------
__global__ __launch_bounds__(256) void attn_kernel(
    const unsigned short* __restrict__ qbuf, const unsigned short* __restrict__ kbuf,
    const unsigned short* __restrict__ vtbuf, unsigned short* __restrict__ obuf)
{
    __shared__ __align__(16) unsigned short sK[2][64 * 64];  // swizzled
    __shared__ __align__(16) unsigned int   sP[4][16 * 36];  // per-wave P^T rows

    const int tid  = threadIdx.x;
    const int wid  = tid >> 6;
    const int lane = tid & 63;
    const int g    = lane >> 4;
    const int c    = lane & 15;

    const int x    = blockIdx.x;
    const int slot = x >> 3;
    const int bh   = (x & 7) * 4 + (slot >> 4);  // XCD-grouped: 4 bh per XCD
    const int pr   = slot & 15;
    const int b    = bh >> 4, h = bh & 15;

    const unsigned short* Qh = qbuf  + (size_t)bh * S_LEN * HDIM;
    const unsigned short* Kh = kbuf  + (size_t)bh * S_LEN * HDIM;
    const unsigned short* Vt = vtbuf + (size_t)bh * HDIM * S_LEN;

    // stage one 64x64 K tile; pre-swizzled global source (rule #21)
    auto stage = [&](int t, int buf) {
#pragma unroll
        for (int i = 0; i < 2; ++i) {
            int cidx = wid * 128 + i * 64 + lane;
            int row  = cidx >> 3;
            int col  = ((cidx & 7) ^ (row & 7)) << 3;
            int base = (wid * 128 + i * 64) * 8;
            load_lds16(Kh + (size_t)(t * 64 + row) * HDIM + col, &sK[buf][base]);
        }
    };

    auto process = [&](int qt) {
        const int qrow0 = qt * 64 + wid * 16;
        const int qg    = qrow0 + c;          // this lane's q row

        // Q fragments (pre-scaled by 0.125*log2e in GEMM): B-frag col=q=c
        bf16x8 aq[2];
#pragma unroll
        for (int kk = 0; kk < 2; ++kk)
            aq[kk] = *(const bf16x8*)&Qh[(size_t)qg * HDIM + kk * 32 + g * 8];

        float m_i = -1e30f, l_i = 0.f;
        f32x4 o[4] = {};

        stage(0, 0);
        asm volatile("s_waitcnt vmcnt(0)" ::: "memory");
        __builtin_amdgcn_s_barrier();

        for (int t = 0; t <= qt; ++t) {
            const int buf = t & 1;

            // V^T fragments direct from global (L2-resident): issue early
            bf16x8 av[4][2];
#pragma unroll
            for (int dblk = 0; dblk < 4; ++dblk)
#pragma unroll
                for (int kk = 0; kk < 2; ++kk)
                    av[dblk][kk] = *(const bf16x8*)
                        &Vt[(size_t)(dblk * 16 + c) * S_LEN + t * 64 + kk * 32 + g * 8];

            // swapped QK^T: D[kv = j*16+g*4+r][q = c]
            f32x4 sc[4] = {};
            __builtin_amdgcn_s_setprio(1);
#pragma unroll
            for (int kk = 0; kk < 2; ++kk) {
                bf16x8 ak[4];
#pragma unroll
                for (int j = 0; j < 4; ++j)
                    ak[j] = *(const bf16x8*)&sK[buf][swz(j * 16 + c, kk * 32 + g * 8)];
#pragma unroll
                for (int j = 0; j < 4; ++j)
                    sc[j] = __builtin_amdgcn_mfma_f32_16x16x32_bf16(
                        ak[j], aq[kk], sc[j], 0, 0, 0);
            }
            __builtin_amdgcn_s_setprio(0);

            // prefetch next K tile (clamped: keeps vmcnt static in loop body)
            stage(t < qt ? t + 1 : t, buf ^ 1);

            // causal mask (diagonal tile only)
            if (t == qt) {
#pragma unroll
                for (int j = 0; j < 4; ++j)
#pragma unroll
                    for (int r = 0; r < 4; ++r)
                        if (t * 64 + j * 16 + g * 4 + r > qg) sc[j][r] = -1e30f;
            }

            // row max for q=c: 15 in-lane fmax + 2 shfl_xor
            float pm = sc[0][0];
#pragma unroll
            for (int j = 0; j < 4; ++j)
#pragma unroll
                for (int r = 0; r < 4; ++r) pm = fmaxf(pm, sc[j][r]);
            pm = fmaxf(pm, __shfl_xor(pm, 16, 64));
            pm = fmaxf(pm, __shfl_xor(pm, 32, 64));
            float m_new = fmaxf(m_i, pm);

            float fac, dm = m_i - m_new;
            asm("v_exp_f32 %0, %1" : "=v"(fac) : "v"(dm));   // exp2 domain

            float rs = 0.f;
#pragma unroll
            for (int j = 0; j < 4; ++j)
#pragma unroll
                for (int r = 0; r < 4; ++r) {
                    float e, a = sc[j][r] - m_new;
                    asm("v_exp_f32 %0, %1" : "=v"(e) : "v"(a));
                    sc[j][r] = e;
                    rs += e;
                }
            rs += __shfl_xor(rs, 16, 64);
            rs += __shfl_xor(rs, 32, 64);
            l_i = l_i * fac + rs;
            m_i = m_new;
#pragma unroll
            for (int dblk = 0; dblk < 4; ++dblk) o[dblk] *= fac;

            // pack P^T -> per-wave LDS rows (stride 36 dwords, b64 writes)
            unsigned int* rowp = &sP[wid][c * 36];
#pragma unroll
            for (int j = 0; j < 4; ++j) {
                uint2 pp;
                pp.x = pkbf(sc[j][0], sc[j][1]);
                pp.y = pkbf(sc[j][2], sc[j][3]);
                *(uint2*)&rowp[j * 8 + g * 2] = pp;   // same-wave DS is in-order
            }

            // PV: A = V^T frag (regs), B = P^T frag from LDS
            __builtin_amdgcn_s_setprio(1);
#pragma unroll
            for (int kk = 0; kk < 2; ++kk) {
                bf16x8 bp = *(const bf16x8*)&sP[wid][c * 36 + kk * 16 + g * 4];
#pragma unroll
                for (int dblk = 0; dblk < 4; ++dblk)
                    o[dblk] = __builtin_amdgcn_mfma_f32_16x16x32_bf16(
                        av[dblk][kk], bp, o[dblk], 0, 0, 0);
            }
            __builtin_amdgcn_s_setprio(0);

            // K_{t+1} visible to all waves before next QK
            asm volatile("s_waitcnt vmcnt(0)" ::: "memory");
            __builtin_amdgcn_s_barrier();
        }

        // epilogue: lane owns row q; 4x 8B stores
        float rl = 1.0f / l_i;
        unsigned short* orow = &obuf[((size_t)(b * S_LEN + qg)) * EMBD + h * HDIM];
#pragma unroll
        for (int dblk = 0; dblk < 4; ++dblk) {
            uint2 pw;
            pw.x = pkbf(o[dblk][0] * rl, o[dblk][1] * rl);
            pw.y = pkbf(o[dblk][2] * rl, o[dblk][3] * rl);
            *(uint2*)&orow[dblk * 16 + g * 4] = pw;
        }
    };

    process(pr);
    process(31 - pr);
}

extern "C" void kernel_launch(void* const* d_in, const int* in_sizes, int n_in,
                              void* d_out, int out_size, void* d_ws, size_t ws_size,
                              hipStream_t stream) {
    const float* hidden = (const float*)d_in[0];  // [2,2048,1024]
    const float* w_attn = (const float*)d_in[1];  // [3072,1024]
    const float* b_attn = (const float*)d_in[2];  // [3072]
    const float* w_proj = (const float*)d_in[3];  // [1024,1024]
    const float* b_proj = (const float*)d_in[4];  // [1024]
    float* out = (float*)d_out;                   // [2,2048,1024] fp32

    unsigned short* Xbf  = (unsigned short*)d_ws;          // 4096*1024
    unsigned short* Wabf = Xbf  + (size_t)ROWS * EMBD;     // 3072*1024
    unsigned short* Wpbf = Wabf + (size_t)3 * EMBD * EMBD; // 1024*1024
    unsigned short* qb   = Wpbf + (size_t)EMBD * EMBD;     // [B,H,S,D] (q pre-scaled)
    unsigned short* kb   = qb + (size_t)BATCHN * NHEAD * S_LEN * HDIM;
    unsigned short* vtb  = kb + (size_t)BATCHN * NHEAD * S_LEN * HDIM; // [B,H,D,S]
    unsigned short* ob   = vtb + (size_t)BATCHN * NHEAD * S_LEN * HDIM; // [B,S,E]

    // fp32 -> bf16 converts
    cvt_f32_bf16<<<2048, 256, 0, stream>>>(hidden, Xbf, ROWS * EMBD);
    cvt_f32_bf16<<<1024, 256, 0, stream>>>(w_attn, Wabf, 3 * EMBD * EMBD);
    cvt_f32_bf16<<<512, 256, 0, stream>>>(w_proj, Wpbf, EMBD * EMBD);

    // QKV projection: q (pre-scaled), k, V^T
    gemm_bt<1><<<dim3(ROWS / 128, 3 * EMBD / 128), 256, 0, stream>>>(
        Xbf, Wabf, b_attn, nullptr, qb, kb, vtb, ROWS, 3 * EMBD, EMBD);

    // causal attention (XCD-grouped, balanced pairs)
    attn_kernel<<<dim3(512), 256, 0, stream>>>(qb, kb, vtb, ob);

    // output projection -> fp32 out
    gemm_bt<0><<<dim3(ROWS / 128, EMBD / 128), 256, 0, stream>>>(
        ob, Wpbf, b_proj, out, nullptr, nullptr, nullptr, ROWS, EMBD, EMBD);
}

// Round 7
// 160.860 us; speedup vs baseline: 1.0587x; 1.0587x over previous
//
#include <hip/hip_runtime.h>
#include <stdint.h>

// Problem constants (GPT-2 attention block)
#define S_LEN  2048
#define EMBD   1024
#define NHEAD  16
#define HDIM   64
#define BATCHN 2
#define ROWS   (BATCHN * S_LEN)   // 4096 = flattened B*S

using bf16x8 = __attribute__((ext_vector_type(8))) __bf16;
using f32x4  = __attribute__((ext_vector_type(4))) float;

typedef const __attribute__((address_space(1))) void* gas_ptr;
typedef __attribute__((address_space(3)))       void* las_ptr;

// Async global->LDS, 16B per lane. LDS dest = wave-uniform base + lane*16.
__device__ __forceinline__ void load_lds16(const void* g, void* l) {
    __builtin_amdgcn_global_load_lds((gas_ptr)(uintptr_t)g, (las_ptr)(uintptr_t)l, 16, 0, 0);
}

// fp32 -> bf16 round-to-nearest-even
__device__ __forceinline__ unsigned short f2bf(float f) {
    unsigned u = __builtin_bit_cast(unsigned, f);
    u += 0x7fffu + ((u >> 16) & 1u);
    return (unsigned short)(u >> 16);
}

// pack 2 floats -> 1 dword of 2 bf16 (lo = a, hi = b); hw cvt_pk (no builtin)
__device__ __forceinline__ unsigned pkbf(float a, float b) {
    unsigned r;
    asm("v_cvt_pk_bf16_f32 %0, %1, %2" : "=v"(r) : "v"(a), "v"(b));
    return r;
}

// Cross-lane reduce over {l, l^16, l^32, l^48}. NOTE: the permlane_swap asm
// version was silently broken — "+v"(a),"+v"(b) with a==b coalesces both to
// ONE register, emitting v_permlane16_swap v5,v5 (in-place row swap, not an
// exchange). shfl_xor is the proven-correct form (R4).
__device__ __forceinline__ float xred_max(float x) {
    x = fmaxf(x, __shfl_xor(x, 16, 64));
    return fmaxf(x, __shfl_xor(x, 32, 64));
}
__device__ __forceinline__ float xred_sum(float x) {
    x += __shfl_xor(x, 16, 64);
    return x + __shfl_xor(x, 32, 64);
}

// XOR-swizzled element offset within a [64][64] bf16 tile (16B-chunk XOR row&7)
__device__ __forceinline__ int swz(int row, int ebase) {
    int byte = (row << 7) + (ebase << 1);
    byte ^= (row & 7) << 4;
    return byte >> 1;
}

__global__ void cvt_f32_bf16(const float* __restrict__ src,
                             unsigned short* __restrict__ dst, int n) {
    int i = blockIdx.x * blockDim.x + threadIdx.x;
    int stride = gridDim.x * blockDim.x;
    for (int idx = i * 4; idx < n; idx += stride * 4) {
        float4 f = *(const float4*)(src + idx);
        uint2 p;
        p.x = (unsigned)f2bf(f.x) | ((unsigned)f2bf(f.y) << 16);
        p.y = (unsigned)f2bf(f.z) | ((unsigned)f2bf(f.w) << 16);
        *(uint2*)(dst + idx) = p;
    }
}

// ---------------------------------------------------------------------------
// bf16 GEMM, C[m][n] = sum_k A[m][k]*B[n][k] (+bias[n]).  A:[M][K] B:[N][K]
// 128x128 tile, BK=64, 4 waves (2x2), each wave 64x64 via 16x16x32 MFMA.
// MODE 0: write fp32 C[m*N+n] (+bias)                 (output projection)
// MODE 1: scatter bf16 q(pre-scaled)/k [B,H,S,D], V^T [B,H,D,S]  (QKV)
// ---------------------------------------------------------------------------
#define SCALE_Q 0.18033688011112042f   // 0.125 * log2(e): softmax in exp2 domain

template <int MODE>
__global__ __launch_bounds__(256) void gemm_bt(
    const unsigned short* __restrict__ A, const unsigned short* __restrict__ B,
    const float* __restrict__ bias, float* __restrict__ Cout,
    unsigned short* __restrict__ qb, unsigned short* __restrict__ kb,
    unsigned short* __restrict__ vb, int M, int N, int K)
{
    __shared__ __align__(16) unsigned short sA[128 * 64];
    __shared__ __align__(16) unsigned short sB[128 * 64];

    const int tid  = threadIdx.x;
    const int wid  = tid >> 6;
    const int lane = tid & 63;
    const int g    = lane >> 4;       // 0..3
    const int c    = lane & 15;       // 0..15
    const int bm   = blockIdx.x * 128;
    const int bn   = blockIdx.y * 128;
    const int wm   = (wid >> 1) * 64;
    const int wn   = (wid & 1) * 64;

    f32x4 acc[4][4] = {};

    for (int k0 = 0; k0 < K; k0 += 64) {
#pragma unroll
        for (int i = 0; i < 4; ++i) {
            int eoff = i * 2048 + tid * 8;
            int row  = eoff >> 6;
            int col  = eoff & 63;
            load_lds16(A + (size_t)(bm + row) * K + k0 + col,
                       &sA[i * 2048 + wid * 512]);
            load_lds16(B + (size_t)(bn + row) * K + k0 + col,
                       &sB[i * 2048 + wid * 512]);
        }
        __syncthreads();
#pragma unroll
        for (int kk = 0; kk < 2; ++kk) {
            bf16x8 af[4], bfr[4];
#pragma unroll
            for (int i = 0; i < 4; ++i)
                af[i] = *(const bf16x8*)&sA[(wm + i * 16 + c) * 64 + kk * 32 + g * 8];
#pragma unroll
            for (int j = 0; j < 4; ++j)
                bfr[j] = *(const bf16x8*)&sB[(wn + j * 16 + c) * 64 + kk * 32 + g * 8];
#pragma unroll
            for (int i = 0; i < 4; ++i)
#pragma unroll
                for (int j = 0; j < 4; ++j)
                    acc[i][j] = __builtin_amdgcn_mfma_f32_16x16x32_bf16(
                        af[i], bfr[j], acc[i][j], 0, 0, 0);
        }
        __syncthreads();
    }

#pragma unroll
    for (int i = 0; i < 4; ++i)
#pragma unroll
        for (int j = 0; j < 4; ++j) {
            int n = bn + wn + j * 16 + c;
            float bv = bias[n];
            if (MODE == 0) {
#pragma unroll
                for (int r = 0; r < 4; ++r) {
                    int m = bm + wm + i * 16 + g * 4 + r;
                    Cout[(size_t)m * N + n] = acc[i][j][r] + bv;
                }
            } else {
                int which = n >> 10, h = (n & 1023) >> 6, d = n & 63;
                if (which < 2) {
                    unsigned short* dst = (which == 0) ? qb : kb;
                    float sc = (which == 0) ? SCALE_Q : 1.0f;
#pragma unroll
                    for (int r = 0; r < 4; ++r) {
                        int m = bm + wm + i * 16 + g * 4 + r;
                        int b = m >> 11, s = m & 2047;
                        dst[(((size_t)b * NHEAD + h) * S_LEN + s) * HDIM + d] =
                            f2bf((acc[i][j][r] + bv) * sc);
                    }
                } else {
                    // V^T [B,H,D,S]: pack 4 consecutive s into one 8B store
                    int m0 = bm + wm + i * 16 + g * 4;
                    int b = m0 >> 11, s0 = m0 & 2047;
                    uint2 p;
                    p.x = pkbf(acc[i][j][0] + bv, acc[i][j][1] + bv);
                    p.y = pkbf(acc[i][j][2] + bv, acc[i][j][3] + bv);
                    *(uint2*)&vb[(((size_t)b * NHEAD + h) * HDIM + d) * S_LEN + s0] = p;
                }
            }
        }
}

// ---------------------------------------------------------------------------
// Flash-style causal attention, swapped-QK^T (lane-local softmax rows).
// Grid: 512 flat, XCD-grouped (4 bh per XCD). Block = 256 thr (4 waves),
// block handles balanced q-tile pair (pr, 31-pr): 33 KV tiles each.
// K: 3-buffer swizzled LDS pipeline, counted vmcnt(2), ONE barrier/tile,
// no vmcnt(0) drain inside the loop (T3/T4). V^T: direct global->reg.
// End of each process: vmcnt(0) drain before re-staging the same buffers.
// Softmax: shfl_xor reductions + defer-rescale (THR=8, exp2 domain).
// ---------------------------------------------------------------------------
__global__ __launch_bounds__(256) void attn_kernel(
    const unsigned short* __restrict__ qbuf, const unsigned short* __restrict__ kbuf,
    const unsigned short* __restrict__ vtbuf, unsigned short* __restrict__ obuf)
{
    __shared__ __align__(16) unsigned short sK[3][64 * 64];  // swizzled, 3-buf
    __shared__ __align__(16) unsigned int   sP[4][16 * 36];  // per-wave P^T rows

    const int tid  = threadIdx.x;
    const int wid  = tid >> 6;
    const int lane = tid & 63;
    const int g    = lane >> 4;
    const int c    = lane & 15;

    const int x    = blockIdx.x;
    const int slot = x >> 3;
    const int bh   = (x & 7) * 4 + (slot >> 4);  // XCD-grouped: 4 bh per XCD
    const int pr   = slot & 15;
    const int b    = bh >> 4, h = bh & 15;

    const unsigned short* Qh = qbuf  + (size_t)bh * S_LEN * HDIM;
    const unsigned short* Kh = kbuf  + (size_t)bh * S_LEN * HDIM;
    const unsigned short* Vt = vtbuf + (size_t)bh * HDIM * S_LEN;

    // stage one 64x64 K tile; pre-swizzled global source (rule #21)
    auto stage = [&](int t, int buf) {
#pragma unroll
        for (int i = 0; i < 2; ++i) {
            int cidx = wid * 128 + i * 64 + lane;
            int row  = cidx >> 3;
            int col  = ((cidx & 7) ^ (row & 7)) << 3;
            int base = (wid * 128 + i * 64) * 8;
            load_lds16(Kh + (size_t)(t * 64 + row) * HDIM + col, &sK[buf][base]);
        }
    };

    auto process = [&](int qt) {
        const int qrow0 = qt * 64 + wid * 16;
        const int qg    = qrow0 + c;          // this lane's q row

        // Q fragments (pre-scaled by 0.125*log2e in GEMM)
        bf16x8 aq[2];
#pragma unroll
        for (int kk = 0; kk < 2; ++kk)
            aq[kk] = *(const bf16x8*)&Qh[(size_t)qg * HDIM + kk * 32 + g * 8];

        float m_i = -1e30f, l_i = 0.f;
        f32x4 o[4] = {};

        stage(0, 0);
        stage(qt >= 1 ? 1 : 0, 1);

        for (int t = 0; t <= qt; ++t) {
            const int buf = t % 3;

            // counted wait: tile t landed, tile t+1 still in flight (2 loads)
            asm volatile("s_waitcnt vmcnt(2)" ::: "memory");
            __builtin_amdgcn_s_barrier();

            // V^T fragments direct from global (L2-resident) — issued BEFORE
            // the next stage so the compiler's V-wait is counted, not a drain
            bf16x8 av[4][2];
#pragma unroll
            for (int dblk = 0; dblk < 4; ++dblk)
#pragma unroll
                for (int kk = 0; kk < 2; ++kk)
                    av[dblk][kk] = *(const bf16x8*)
                        &Vt[(size_t)(dblk * 16 + c) * S_LEN + t * 64 + kk * 32 + g * 8];

            // prefetch tile t+2 (clamped: static load count per iteration)
            stage(t + 2 <= qt ? t + 2 : qt, (t + 2) % 3);

            // swapped QK^T: D[kv = j*16+g*4+r][q = c]
            f32x4 sc[4] = {};
            __builtin_amdgcn_s_setprio(1);
#pragma unroll
            for (int kk = 0; kk < 2; ++kk) {
                bf16x8 ak[4];
#pragma unroll
                for (int j = 0; j < 4; ++j)
                    ak[j] = *(const bf16x8*)&sK[buf][swz(j * 16 + c, kk * 32 + g * 8)];
#pragma unroll
                for (int j = 0; j < 4; ++j)
                    sc[j] = __builtin_amdgcn_mfma_f32_16x16x32_bf16(
                        ak[j], aq[kk], sc[j], 0, 0, 0);
            }
            __builtin_amdgcn_s_setprio(0);

            // causal mask (diagonal tile only)
            if (t == qt) {
#pragma unroll
                for (int j = 0; j < 4; ++j)
#pragma unroll
                    for (int r = 0; r < 4; ++r)
                        if (t * 64 + j * 16 + g * 4 + r > qg) sc[j][r] = -1e30f;
            }

            // row max: pairwise tree (depth 4) + cross-lane reduce
            float x01 = fmaxf(fmaxf(sc[0][0], sc[0][1]), fmaxf(sc[0][2], sc[0][3]));
            float x23 = fmaxf(fmaxf(sc[1][0], sc[1][1]), fmaxf(sc[1][2], sc[1][3]));
            float x45 = fmaxf(fmaxf(sc[2][0], sc[2][1]), fmaxf(sc[2][2], sc[2][3]));
            float x67 = fmaxf(fmaxf(sc[3][0], sc[3][1]), fmaxf(sc[3][2], sc[3][3]));
            float pm  = xred_max(fmaxf(fmaxf(x01, x23), fmaxf(x45, x67)));

            // defer-rescale (T13): skip the O-pass unless max grew by >8 (2^8)
            if (__any(pm > m_i + 8.0f)) {
                float m_new = fmaxf(m_i, pm);
                float fac, dm = m_i - m_new;
                asm("v_exp_f32 %0, %1" : "=v"(fac) : "v"(dm));
                l_i *= fac;
                m_i  = m_new;
#pragma unroll
                for (int dblk = 0; dblk < 4; ++dblk) o[dblk] *= fac;
            }

            // P = exp2(S - m_i), tree-summed
            float e[4][4];
#pragma unroll
            for (int j = 0; j < 4; ++j)
#pragma unroll
                for (int r = 0; r < 4; ++r) {
                    float a = sc[j][r] - m_i;
                    asm("v_exp_f32 %0, %1" : "=v"(e[j][r]) : "v"(a));
                }
            float s01 = (e[0][0] + e[0][1]) + (e[0][2] + e[0][3]);
            float s23 = (e[1][0] + e[1][1]) + (e[1][2] + e[1][3]);
            float s45 = (e[2][0] + e[2][1]) + (e[2][2] + e[2][3]);
            float s67 = (e[3][0] + e[3][1]) + (e[3][2] + e[3][3]);
            l_i += xred_sum((s01 + s23) + (s45 + s67));

            // pack P^T -> per-wave LDS rows (stride 36 dwords, b64 writes)
            unsigned int* rowp = &sP[wid][c * 36];
#pragma unroll
            for (int j = 0; j < 4; ++j) {
                uint2 pp;
                pp.x = pkbf(e[j][0], e[j][1]);
                pp.y = pkbf(e[j][2], e[j][3]);
                *(uint2*)&rowp[j * 8 + g * 2] = pp;   // same-wave DS is in-order
            }

            // PV: A = V^T frag (regs), B = P^T frag from LDS
            __builtin_amdgcn_s_setprio(1);
#pragma unroll
            for (int kk = 0; kk < 2; ++kk) {
                bf16x8 bp = *(const bf16x8*)&sP[wid][c * 36 + kk * 16 + g * 4];
#pragma unroll
                for (int dblk = 0; dblk < 4; ++dblk)
                    o[dblk] = __builtin_amdgcn_mfma_f32_16x16x32_bf16(
                        av[dblk][kk], bp, o[dblk], 0, 0, 0);
            }
            __builtin_amdgcn_s_setprio(0);
            // no trailing drain: next iteration's vmcnt(2)+barrier gates reuse
        }

        // drain: clamped tail prefetches target buffers the next process()
        // immediately re-stages; all must land before new stages are issued
        asm volatile("s_waitcnt vmcnt(0)" ::: "memory");
        __builtin_amdgcn_s_barrier();

        // epilogue: lane owns row q; 4x 8B stores
        float rl = 1.0f / l_i;
        unsigned short* orow = &obuf[((size_t)(b * S_LEN + qg)) * EMBD + h * HDIM];
#pragma unroll
        for (int dblk = 0; dblk < 4; ++dblk) {
            uint2 pw;
            pw.x = pkbf(o[dblk][0] * rl, o[dblk][1] * rl);
            pw.y = pkbf(o[dblk][2] * rl, o[dblk][3] * rl);
            *(uint2*)&orow[dblk * 16 + g * 4] = pw;
        }
    };

    process(pr);
    process(31 - pr);
}

extern "C" void kernel_launch(void* const* d_in, const int* in_sizes, int n_in,
                              void* d_out, int out_size, void* d_ws, size_t ws_size,
                              hipStream_t stream) {
    const float* hidden = (const float*)d_in[0];  // [2,2048,1024]
    const float* w_attn = (const float*)d_in[1];  // [3072,1024]
    const float* b_attn = (const float*)d_in[2];  // [3072]
    const float* w_proj = (const float*)d_in[3];  // [1024,1024]
    const float* b_proj = (const float*)d_in[4];  // [1024]
    float* out = (float*)d_out;                   // [2,2048,1024] fp32

    unsigned short* Xbf  = (unsigned short*)d_ws;          // 4096*1024
    unsigned short* Wabf = Xbf  + (size_t)ROWS * EMBD;     // 3072*1024
    unsigned short* Wpbf = Wabf + (size_t)3 * EMBD * EMBD; // 1024*1024
    unsigned short* qb   = Wpbf + (size_t)EMBD * EMBD;     // [B,H,S,D] (q pre-scaled)
    unsigned short* kb   = qb + (size_t)BATCHN * NHEAD * S_LEN * HDIM;
    unsigned short* vtb  = kb + (size_t)BATCHN * NHEAD * S_LEN * HDIM; // [B,H,D,S]
    unsigned short* ob   = vtb + (size_t)BATCHN * NHEAD * S_LEN * HDIM; // [B,S,E]

    // fp32 -> bf16 converts
    cvt_f32_bf16<<<2048, 256, 0, stream>>>(hidden, Xbf, ROWS * EMBD);
    cvt_f32_bf16<<<1024, 256, 0, stream>>>(w_attn, Wabf, 3 * EMBD * EMBD);
    cvt_f32_bf16<<<512, 256, 0, stream>>>(w_proj, Wpbf, EMBD * EMBD);

    // QKV projection: q (pre-scaled), k, V^T
    gemm_bt<1><<<dim3(ROWS / 128, 3 * EMBD / 128), 256, 0, stream>>>(
        Xbf, Wabf, b_attn, nullptr, qb, kb, vtb, ROWS, 3 * EMBD, EMBD);

    // causal attention (XCD-grouped, balanced pairs)
    attn_kernel<<<dim3(512), 256, 0, stream>>>(qb, kb, vtb, ob);

    // output projection -> fp32 out
    gemm_bt<0><<<dim3(ROWS / 128, EMBD / 128), 256, 0, stream>>>(
        ob, Wpbf, b_proj, out, nullptr, nullptr, nullptr, ROWS, EMBD, EMBD);
}

// Round 8
// 160.603 us; speedup vs baseline: 1.0604x; 1.0016x over previous
//
#include <hip/hip_runtime.h>
#include <stdint.h>

// Problem constants (GPT-2 attention block)
#define S_LEN  2048
#define EMBD   1024
#define NHEAD  16
#define HDIM   64
#define BATCHN 2
#define ROWS   (BATCHN * S_LEN)   // 4096 = flattened B*S

using bf16x8 = __attribute__((ext_vector_type(8))) __bf16;
using f32x4  = __attribute__((ext_vector_type(4))) float;

typedef const __attribute__((address_space(1))) void* gas_ptr;
typedef __attribute__((address_space(3)))       void* las_ptr;

// Async global->LDS, 16B per lane. LDS dest = wave-uniform base + lane*16.
__device__ __forceinline__ void load_lds16(const void* g, void* l) {
    __builtin_amdgcn_global_load_lds((gas_ptr)(uintptr_t)g, (las_ptr)(uintptr_t)l, 16, 0, 0);
}

// fp32 -> bf16 round-to-nearest-even
__device__ __forceinline__ unsigned short f2bf(float f) {
    unsigned u = __builtin_bit_cast(unsigned, f);
    u += 0x7fffu + ((u >> 16) & 1u);
    return (unsigned short)(u >> 16);
}

// pack 2 floats -> 1 dword of 2 bf16 (lo = a, hi = b); hw cvt_pk (no builtin)
__device__ __forceinline__ unsigned pkbf(float a, float b) {
    unsigned r;
    asm("v_cvt_pk_bf16_f32 %0, %1, %2" : "=v"(r) : "v"(a), "v"(b));
    return r;
}

// Cross-lane reduce over {l, l^16, l^32, l^48} via shfl_xor (proven R4 form;
// the permlane_swap asm version coalesced its tied operands into ONE register
// and silently row-swapped instead of exchanging — R5/R6 bug).
__device__ __forceinline__ float xred_max(float x) {
    x = fmaxf(x, __shfl_xor(x, 16, 64));
    return fmaxf(x, __shfl_xor(x, 32, 64));
}
__device__ __forceinline__ float xred_sum(float x) {
    x += __shfl_xor(x, 16, 64);
    return x + __shfl_xor(x, 32, 64);
}

// XOR-swizzled element offset within a [64][64] bf16 tile (16B-chunk XOR row&7)
__device__ __forceinline__ int swz(int row, int ebase) {
    int byte = (row << 7) + (ebase << 1);
    byte ^= (row & 7) << 4;
    return byte >> 1;
}

// Merged fp32->bf16 convert for 3 sources; destinations are contiguous in ws.
__global__ void cvt3_f32_bf16(const float* __restrict__ s0,
                              const float* __restrict__ s1,
                              const float* __restrict__ s2,
                              unsigned short* __restrict__ d,
                              int n0, int n01, int ntot) {
    int i = blockIdx.x * blockDim.x + threadIdx.x;
    int stride = gridDim.x * blockDim.x;
    for (int idx = i * 4; idx < ntot; idx += stride * 4) {
        const float* s; int off;
        if (idx < n0)       { s = s0; off = idx; }
        else if (idx < n01) { s = s1; off = idx - n0; }
        else                { s = s2; off = idx - n01; }
        float4 f = *(const float4*)(s + off);
        uint2 p;
        p.x = (unsigned)f2bf(f.x) | ((unsigned)f2bf(f.y) << 16);
        p.y = (unsigned)f2bf(f.z) | ((unsigned)f2bf(f.w) << 16);
        *(uint2*)(d + idx) = p;
    }
}

// ---------------------------------------------------------------------------
// bf16 GEMM, C[m][n] = sum_k A[m][k]*B[n][k] (+bias[n]).  A:[M][K] B:[N][K]
// 128x128 tile, BK=64, 4 waves (2x2), each wave 64x64 via 16x16x32 MFMA.
// MODE 0: write fp32 C[m*N+n] (+bias)                 (output projection)
// MODE 1: scatter bf16 q(pre-scaled)/k [B,H,S,D], V^T [B,H,D,S]  (QKV)
// ---------------------------------------------------------------------------
#define SCALE_Q 0.18033688011112042f   // 0.125 * log2(e): softmax in exp2 domain

template <int MODE>
__global__ __launch_bounds__(256) void gemm_bt(
    const unsigned short* __restrict__ A, const unsigned short* __restrict__ B,
    const float* __restrict__ bias, float* __restrict__ Cout,
    unsigned short* __restrict__ qb, unsigned short* __restrict__ kb,
    unsigned short* __restrict__ vb, int M, int N, int K)
{
    __shared__ __align__(16) unsigned short sA[128 * 64];
    __shared__ __align__(16) unsigned short sB[128 * 64];

    const int tid  = threadIdx.x;
    const int wid  = tid >> 6;
    const int lane = tid & 63;
    const int g    = lane >> 4;       // 0..3
    const int c    = lane & 15;       // 0..15
    const int bm   = blockIdx.x * 128;
    const int bn   = blockIdx.y * 128;
    const int wm   = (wid >> 1) * 64;
    const int wn   = (wid & 1) * 64;

    f32x4 acc[4][4] = {};

    for (int k0 = 0; k0 < K; k0 += 64) {
#pragma unroll
        for (int i = 0; i < 4; ++i) {
            int eoff = i * 2048 + tid * 8;
            int row  = eoff >> 6;
            int col  = eoff & 63;
            load_lds16(A + (size_t)(bm + row) * K + k0 + col,
                       &sA[i * 2048 + wid * 512]);
            load_lds16(B + (size_t)(bn + row) * K + k0 + col,
                       &sB[i * 2048 + wid * 512]);
        }
        __syncthreads();
#pragma unroll
        for (int kk = 0; kk < 2; ++kk) {
            bf16x8 af[4], bfr[4];
#pragma unroll
            for (int i = 0; i < 4; ++i)
                af[i] = *(const bf16x8*)&sA[(wm + i * 16 + c) * 64 + kk * 32 + g * 8];
#pragma unroll
            for (int j = 0; j < 4; ++j)
                bfr[j] = *(const bf16x8*)&sB[(wn + j * 16 + c) * 64 + kk * 32 + g * 8];
#pragma unroll
            for (int i = 0; i < 4; ++i)
#pragma unroll
                for (int j = 0; j < 4; ++j)
                    acc[i][j] = __builtin_amdgcn_mfma_f32_16x16x32_bf16(
                        af[i], bfr[j], acc[i][j], 0, 0, 0);
        }
        __syncthreads();
    }

#pragma unroll
    for (int i = 0; i < 4; ++i)
#pragma unroll
        for (int j = 0; j < 4; ++j) {
            int n = bn + wn + j * 16 + c;
            float bv = bias[n];
            if (MODE == 0) {
#pragma unroll
                for (int r = 0; r < 4; ++r) {
                    int m = bm + wm + i * 16 + g * 4 + r;
                    Cout[(size_t)m * N + n] = acc[i][j][r] + bv;
                }
            } else {
                int which = n >> 10, h = (n & 1023) >> 6, d = n & 63;
                if (which < 2) {
                    unsigned short* dst = (which == 0) ? qb : kb;
                    float sc = (which == 0) ? SCALE_Q : 1.0f;
#pragma unroll
                    for (int r = 0; r < 4; ++r) {
                        int m = bm + wm + i * 16 + g * 4 + r;
                        int b = m >> 11, s = m & 2047;
                        dst[(((size_t)b * NHEAD + h) * S_LEN + s) * HDIM + d] =
                            f2bf((acc[i][j][r] + bv) * sc);
                    }
                } else {
                    // V^T [B,H,D,S]: pack 4 consecutive s into one 8B store
                    int m0 = bm + wm + i * 16 + g * 4;
                    int b = m0 >> 11, s0 = m0 & 2047;
                    uint2 p;
                    p.x = pkbf(acc[i][j][0] + bv, acc[i][j][1] + bv);
                    p.y = pkbf(acc[i][j][2] + bv, acc[i][j][3] + bv);
                    *(uint2*)&vb[(((size_t)b * NHEAD + h) * HDIM + d) * S_LEN + s0] = p;
                }
            }
        }
}

// ---------------------------------------------------------------------------
// Flash-style causal attention, swapped-QK^T (lane-local softmax rows).
// Grid: 1024 flat — ONE q-tile per block, 4 blocks/CU (occupancy 2x vs R7).
// Mapping: w = x&255 (constant per CU under round-robin dispatch), slot=x>>8;
// each CU's 4 slots get qt {31-c, 23-c, c, c+8} = 66 tiles (balanced), all
// with the SAME bh (K/V L1 reuse). bh grouped 4-per-XCD via w&7.
// K: 3-buffer swizzled LDS pipeline, counted vmcnt(2), ONE barrier/tile.
// V^T: direct global->reg. Softmax hot path has ZERO cross-lane ops:
// per-lane partial l (combined once in epilogue), row-max xred only inside
// the rarely-taken defer-rescale branch (THR=8, exp2 domain).
// ---------------------------------------------------------------------------
__global__ __launch_bounds__(256) void attn_kernel(
    const unsigned short* __restrict__ qbuf, const unsigned short* __restrict__ kbuf,
    const unsigned short* __restrict__ vtbuf, unsigned short* __restrict__ obuf)
{
    __shared__ __align__(16) unsigned short sK[3][64 * 64];  // swizzled, 3-buf
    __shared__ __align__(16) unsigned int   sP[4][16 * 36];  // per-wave P^T rows

    const int tid  = threadIdx.x;
    const int wid  = tid >> 6;
    const int lane = tid & 63;
    const int g    = lane >> 4;
    const int c    = lane & 15;

    const int x    = blockIdx.x;                 // [0,1024)
    const int w    = x & 255;
    const int slot = x >> 8;                     // 0..3
    const int cc2  = w >> 5;                     // 0..7
    const int qt   = (slot < 2) ? (31 - 8 * slot - cc2) : (cc2 + 8 * (slot - 2));
    const int bh   = ((w & 7) << 2) | ((w >> 3) & 3);
    const int b    = bh >> 4, h = bh & 15;

    const unsigned short* Qh = qbuf  + (size_t)bh * S_LEN * HDIM;
    const unsigned short* Kh = kbuf  + (size_t)bh * S_LEN * HDIM;
    const unsigned short* Vt = vtbuf + (size_t)bh * HDIM * S_LEN;

    // stage one 64x64 K tile; pre-swizzled global source (rule #21)
    auto stage = [&](int t, int buf) {
#pragma unroll
        for (int i = 0; i < 2; ++i) {
            int cidx = wid * 128 + i * 64 + lane;
            int row  = cidx >> 3;
            int col  = ((cidx & 7) ^ (row & 7)) << 3;
            int base = (wid * 128 + i * 64) * 8;
            load_lds16(Kh + (size_t)(t * 64 + row) * HDIM + col, &sK[buf][base]);
        }
    };

    const int qrow0 = qt * 64 + wid * 16;
    const int qg    = qrow0 + c;          // this lane's q row

    // Q fragments (pre-scaled by 0.125*log2e in GEMM)
    bf16x8 aq[2];
#pragma unroll
    for (int kk = 0; kk < 2; ++kk)
        aq[kk] = *(const bf16x8*)&Qh[(size_t)qg * HDIM + kk * 32 + g * 8];

    float m_i = -1e30f, l_i = 0.f;   // l_i is a PER-LANE partial (combined in epilogue)
    f32x4 o[4] = {};

    stage(0, 0);
    stage(qt >= 1 ? 1 : 0, 1);

    for (int t = 0; t <= qt; ++t) {
        const int buf = t % 3;

        // counted wait: tile t landed, tile t+1 still in flight (2 loads)
        asm volatile("s_waitcnt vmcnt(2)" ::: "memory");
        __builtin_amdgcn_s_barrier();

        // V^T fragments direct from global (L2-resident) — issued BEFORE
        // the next stage so the compiler's V-wait is counted, not a drain
        bf16x8 av[4][2];
#pragma unroll
        for (int dblk = 0; dblk < 4; ++dblk)
#pragma unroll
            for (int kk = 0; kk < 2; ++kk)
                av[dblk][kk] = *(const bf16x8*)
                    &Vt[(size_t)(dblk * 16 + c) * S_LEN + t * 64 + kk * 32 + g * 8];

        // prefetch tile t+2 (clamped: static load count per iteration)
        stage(t + 2 <= qt ? t + 2 : qt, (t + 2) % 3);

        // swapped QK^T: D[kv = j*16+g*4+r][q = c]
        f32x4 sc[4] = {};
        __builtin_amdgcn_s_setprio(1);
#pragma unroll
        for (int kk = 0; kk < 2; ++kk) {
            bf16x8 ak[4];
#pragma unroll
            for (int j = 0; j < 4; ++j)
                ak[j] = *(const bf16x8*)&sK[buf][swz(j * 16 + c, kk * 32 + g * 8)];
#pragma unroll
            for (int j = 0; j < 4; ++j)
                sc[j] = __builtin_amdgcn_mfma_f32_16x16x32_bf16(
                    ak[j], aq[kk], sc[j], 0, 0, 0);
        }
        __builtin_amdgcn_s_setprio(0);

        // causal mask (diagonal tile only)
        if (t == qt) {
#pragma unroll
            for (int j = 0; j < 4; ++j)
#pragma unroll
                for (int r = 0; r < 4; ++r)
                    if (t * 64 + j * 16 + g * 4 + r > qg) sc[j][r] = -1e30f;
        }

        // LOCAL max over this lane's 16 values (tree, no cross-lane)
        float x01 = fmaxf(fmaxf(sc[0][0], sc[0][1]), fmaxf(sc[0][2], sc[0][3]));
        float x23 = fmaxf(fmaxf(sc[1][0], sc[1][1]), fmaxf(sc[1][2], sc[1][3]));
        float x45 = fmaxf(fmaxf(sc[2][0], sc[2][1]), fmaxf(sc[2][2], sc[2][3]));
        float x67 = fmaxf(fmaxf(sc[3][0], sc[3][1]), fmaxf(sc[3][2], sc[3][3]));
        float pm  = fmaxf(fmaxf(x01, x23), fmaxf(x45, x67));

        // defer-rescale (T13): cross-lane max ONLY when some row grew by >8.
        // Trigger is wave-uniform (__any), so m_i stays identical across the
        // 4 g-lanes of each q-row — required for consistent P scaling.
        if (__any(pm > m_i + 8.0f)) {
            float pmr   = xred_max(pm);
            float m_new = fmaxf(m_i, pmr);
            float fac, dm = m_i - m_new;
            asm("v_exp_f32 %0, %1" : "=v"(fac) : "v"(dm));   // exp2 domain
            l_i *= fac;
            m_i  = m_new;
#pragma unroll
            for (int dblk = 0; dblk < 4; ++dblk) o[dblk] *= fac;
        }

        // P = exp2(S - m_i); per-lane partial sum (no cross-lane)
        float e[4][4];
#pragma unroll
        for (int j = 0; j < 4; ++j)
#pragma unroll
            for (int r = 0; r < 4; ++r) {
                float a = sc[j][r] - m_i;
                asm("v_exp_f32 %0, %1" : "=v"(e[j][r]) : "v"(a));
            }
        float s01 = (e[0][0] + e[0][1]) + (e[0][2] + e[0][3]);
        float s23 = (e[1][0] + e[1][1]) + (e[1][2] + e[1][3]);
        float s45 = (e[2][0] + e[2][1]) + (e[2][2] + e[2][3]);
        float s67 = (e[3][0] + e[3][1]) + (e[3][2] + e[3][3]);
        l_i += (s01 + s23) + (s45 + s67);

        // pack P^T -> per-wave LDS rows (stride 36 dwords, b64 writes)
        unsigned int* rowp = &sP[wid][c * 36];
#pragma unroll
        for (int j = 0; j < 4; ++j) {
            uint2 pp;
            pp.x = pkbf(e[j][0], e[j][1]);
            pp.y = pkbf(e[j][2], e[j][3]);
            *(uint2*)&rowp[j * 8 + g * 2] = pp;   // same-wave DS is in-order
        }

        // PV: A = V^T frag (regs), B = P^T frag from LDS
        __builtin_amdgcn_s_setprio(1);
#pragma unroll
        for (int kk = 0; kk < 2; ++kk) {
            bf16x8 bp = *(const bf16x8*)&sP[wid][c * 36 + kk * 16 + g * 4];
#pragma unroll
            for (int dblk = 0; dblk < 4; ++dblk)
                o[dblk] = __builtin_amdgcn_mfma_f32_16x16x32_bf16(
                    av[dblk][kk], bp, o[dblk], 0, 0, 0);
        }
        __builtin_amdgcn_s_setprio(0);
        // no trailing drain: next iteration's vmcnt(2)+barrier gates reuse
    }

    // drain before endpgm: in-flight clamped tail prefetches must land before
    // this workgroup's LDS is recycled for a new block
    asm volatile("s_waitcnt vmcnt(0)" ::: "memory");

    // epilogue: combine per-lane l partials across the 4 g-lanes (once)
    float l_full = xred_sum(l_i);
    float rl = 1.0f / l_full;
    unsigned short* orow = &obuf[((size_t)(b * S_LEN + qg)) * EMBD + h * HDIM];
#pragma unroll
    for (int dblk = 0; dblk < 4; ++dblk) {
        uint2 pw;
        pw.x = pkbf(o[dblk][0] * rl, o[dblk][1] * rl);
        pw.y = pkbf(o[dblk][2] * rl, o[dblk][3] * rl);
        *(uint2*)&orow[dblk * 16 + g * 4] = pw;
    }
}

extern "C" void kernel_launch(void* const* d_in, const int* in_sizes, int n_in,
                              void* d_out, int out_size, void* d_ws, size_t ws_size,
                              hipStream_t stream) {
    const float* hidden = (const float*)d_in[0];  // [2,2048,1024]
    const float* w_attn = (const float*)d_in[1];  // [3072,1024]
    const float* b_attn = (const float*)d_in[2];  // [3072]
    const float* w_proj = (const float*)d_in[3];  // [1024,1024]
    const float* b_proj = (const float*)d_in[4];  // [1024]
    float* out = (float*)d_out;                   // [2,2048,1024] fp32

    unsigned short* Xbf  = (unsigned short*)d_ws;          // 4096*1024
    unsigned short* Wabf = Xbf  + (size_t)ROWS * EMBD;     // 3072*1024
    unsigned short* Wpbf = Wabf + (size_t)3 * EMBD * EMBD; // 1024*1024
    unsigned short* qb   = Wpbf + (size_t)EMBD * EMBD;     // [B,H,S,D] (q pre-scaled)
    unsigned short* kb   = qb + (size_t)BATCHN * NHEAD * S_LEN * HDIM;
    unsigned short* vtb  = kb + (size_t)BATCHN * NHEAD * S_LEN * HDIM; // [B,H,D,S]
    unsigned short* ob   = vtb + (size_t)BATCHN * NHEAD * S_LEN * HDIM; // [B,S,E]

    // fp32 -> bf16 converts (single launch; dsts contiguous in ws)
    const int n0   = ROWS * EMBD;             // 4.19M
    const int n01  = n0 + 3 * EMBD * EMBD;    // +3.15M
    const int ntot = n01 + EMBD * EMBD;       // +1.05M
    cvt3_f32_bf16<<<2048, 256, 0, stream>>>(hidden, w_attn, w_proj, Xbf,
                                            n0, n01, ntot);

    // QKV projection: q (pre-scaled), k, V^T
    gemm_bt<1><<<dim3(ROWS / 128, 3 * EMBD / 128), 256, 0, stream>>>(
        Xbf, Wabf, b_attn, nullptr, qb, kb, vtb, ROWS, 3 * EMBD, EMBD);

    // causal attention (1024 blocks, 4/CU; per-CU qt sets balanced at 66 tiles)
    attn_kernel<<<dim3(1024), 256, 0, stream>>>(qb, kb, vtb, ob);

    // output projection -> fp32 out
    gemm_bt<0><<<dim3(ROWS / 128, EMBD / 128), 256, 0, stream>>>(
        ob, Wpbf, b_proj, out, nullptr, nullptr, nullptr, ROWS, EMBD, EMBD);
}

// Round 9
// 140.443 us; speedup vs baseline: 1.2126x; 1.1435x over previous
//
#include <hip/hip_runtime.h>
#include <stdint.h>

// Problem constants (GPT-2 attention block)
#define S_LEN  2048
#define EMBD   1024
#define NHEAD  16
#define HDIM   64
#define BATCHN 2
#define ROWS   (BATCHN * S_LEN)   // 4096 = flattened B*S

using bf16x8 = __attribute__((ext_vector_type(8))) __bf16;
using f32x4  = __attribute__((ext_vector_type(4))) float;
using f32x16 = __attribute__((ext_vector_type(16))) float;
using u32x4  = __attribute__((ext_vector_type(4))) unsigned;

typedef const __attribute__((address_space(1))) void* gas_ptr;
typedef __attribute__((address_space(3)))       void* las_ptr;

// Async global->LDS, 16B per lane. LDS dest = wave-uniform base + lane*16.
__device__ __forceinline__ void load_lds16(const void* g, void* l) {
    __builtin_amdgcn_global_load_lds((gas_ptr)(uintptr_t)g, (las_ptr)(uintptr_t)l, 16, 0, 0);
}

// fp32 -> bf16 round-to-nearest-even
__device__ __forceinline__ unsigned short f2bf(float f) {
    unsigned u = __builtin_bit_cast(unsigned, f);
    u += 0x7fffu + ((u >> 16) & 1u);
    return (unsigned short)(u >> 16);
}

// pack 2 floats -> 1 dword of 2 bf16 (lo = a, hi = b); hw cvt_pk (no builtin)
__device__ __forceinline__ unsigned pkbf(float a, float b) {
    unsigned r;
    asm("v_cvt_pk_bf16_f32 %0, %1, %2" : "=v"(r) : "v"(a), "v"(b));
    return r;
}

// XOR-swizzled element offset within a [64][64] bf16 tile (16B-chunk XOR row&7)
__device__ __forceinline__ int swz(int row, int ebase) {
    int byte = (row << 7) + (ebase << 1);
    byte ^= (row & 7) << 4;
    return byte >> 1;
}

// Merged fp32->bf16 convert for 3 sources; destinations are contiguous in ws.
__global__ void cvt3_f32_bf16(const float* __restrict__ s0,
                              const float* __restrict__ s1,
                              const float* __restrict__ s2,
                              unsigned short* __restrict__ d,
                              int n0, int n01, int ntot) {
    int i = blockIdx.x * blockDim.x + threadIdx.x;
    int stride = gridDim.x * blockDim.x;
    for (int idx = i * 4; idx < ntot; idx += stride * 4) {
        const float* s; int off;
        if (idx < n0)       { s = s0; off = idx; }
        else if (idx < n01) { s = s1; off = idx - n0; }
        else                { s = s2; off = idx - n01; }
        float4 f = *(const float4*)(s + off);
        uint2 p;
        p.x = (unsigned)f2bf(f.x) | ((unsigned)f2bf(f.y) << 16);
        p.y = (unsigned)f2bf(f.z) | ((unsigned)f2bf(f.w) << 16);
        *(uint2*)(d + idx) = p;
    }
}

// ---------------------------------------------------------------------------
// bf16 GEMM, C[m][n] = sum_k A[m][k]*B[n][k] (+bias[n]).  A:[M][K] B:[N][K]
// 128x128 tile, BK=64, 4 waves (2x2), each wave 64x64 via 16x16x32 MFMA.
// MODE 0: write fp32 C[m*N+n] (+bias)                 (output projection)
// MODE 1: scatter bf16 q(pre-scaled)/k [B,H,S,D], V^T [B,H,D,S]  (QKV)
// ---------------------------------------------------------------------------
#define SCALE_Q 0.18033688011112042f   // 0.125 * log2(e): softmax in exp2 domain

template <int MODE>
__global__ __launch_bounds__(256) void gemm_bt(
    const unsigned short* __restrict__ A, const unsigned short* __restrict__ B,
    const float* __restrict__ bias, float* __restrict__ Cout,
    unsigned short* __restrict__ qb, unsigned short* __restrict__ kb,
    unsigned short* __restrict__ vb, int M, int N, int K)
{
    __shared__ __align__(16) unsigned short sA[128 * 64];
    __shared__ __align__(16) unsigned short sB[128 * 64];

    const int tid  = threadIdx.x;
    const int wid  = tid >> 6;
    const int lane = tid & 63;
    const int g    = lane >> 4;       // 0..3
    const int c    = lane & 15;       // 0..15
    const int bm   = blockIdx.x * 128;
    const int bn   = blockIdx.y * 128;
    const int wm   = (wid >> 1) * 64;
    const int wn   = (wid & 1) * 64;

    f32x4 acc[4][4] = {};

    for (int k0 = 0; k0 < K; k0 += 64) {
#pragma unroll
        for (int i = 0; i < 4; ++i) {
            int eoff = i * 2048 + tid * 8;
            int row  = eoff >> 6;
            int col  = eoff & 63;
            load_lds16(A + (size_t)(bm + row) * K + k0 + col,
                       &sA[i * 2048 + wid * 512]);
            load_lds16(B + (size_t)(bn + row) * K + k0 + col,
                       &sB[i * 2048 + wid * 512]);
        }
        __syncthreads();
#pragma unroll
        for (int kk = 0; kk < 2; ++kk) {
            bf16x8 af[4], bfr[4];
#pragma unroll
            for (int i = 0; i < 4; ++i)
                af[i] = *(const bf16x8*)&sA[(wm + i * 16 + c) * 64 + kk * 32 + g * 8];
#pragma unroll
            for (int j = 0; j < 4; ++j)
                bfr[j] = *(const bf16x8*)&sB[(wn + j * 16 + c) * 64 + kk * 32 + g * 8];
#pragma unroll
            for (int i = 0; i < 4; ++i)
#pragma unroll
                for (int j = 0; j < 4; ++j)
                    acc[i][j] = __builtin_amdgcn_mfma_f32_16x16x32_bf16(
                        af[i], bfr[j], acc[i][j], 0, 0, 0);
        }
        __syncthreads();
    }

#pragma unroll
    for (int i = 0; i < 4; ++i)
#pragma unroll
        for (int j = 0; j < 4; ++j) {
            int n = bn + wn + j * 16 + c;
            float bv = bias[n];
            if (MODE == 0) {
#pragma unroll
                for (int r = 0; r < 4; ++r) {
                    int m = bm + wm + i * 16 + g * 4 + r;
                    Cout[(size_t)m * N + n] = acc[i][j][r] + bv;
                }
            } else {
                int which = n >> 10, h = (n & 1023) >> 6, d = n & 63;
                if (which < 2) {
                    unsigned short* dst = (which == 0) ? qb : kb;
                    float sc = (which == 0) ? SCALE_Q : 1.0f;
#pragma unroll
                    for (int r = 0; r < 4; ++r) {
                        int m = bm + wm + i * 16 + g * 4 + r;
                        int b = m >> 11, s = m & 2047;
                        dst[(((size_t)b * NHEAD + h) * S_LEN + s) * HDIM + d] =
                            f2bf((acc[i][j][r] + bv) * sc);
                    }
                } else {
                    // V^T [B,H,D,S]: pack 4 consecutive s into one 8B store
                    int m0 = bm + wm + i * 16 + g * 4;
                    int b = m0 >> 11, s0 = m0 & 2047;
                    uint2 p;
                    p.x = pkbf(acc[i][j][0] + bv, acc[i][j][1] + bv);
                    p.y = pkbf(acc[i][j][2] + bv, acc[i][j][3] + bv);
                    *(uint2*)&vb[(((size_t)b * NHEAD + h) * HDIM + d) * S_LEN + s0] = p;
                }
            }
        }
}

// ---------------------------------------------------------------------------
// Flash-style causal attention — 32x32 MFMA structure (m214-class).
// Grid: 512 blocks x 256 thr (4 waves). Wave owns 32 q-rows; block = 128.
// LPT order: s = 15 - (x>>5) (heavy supers first); bh = x&31 -> XCD = bh%8.
// Swapped QK^T (D[kv][q=lane&31]); q-row owned by a hi-lane pair (lane^32).
// K and V^T co-staged into swizzled LDS (3-buffer, counted vmcnt(4), one
// barrier/tile). P stays IN REGISTERS: cvt_pk pairs + 4 shfl_xor(32) + hi-
// selects per 16-kv slice build the PV B-fragment (no LDS round-trip).
// 32x32x16 layouts (m74/m101/m89-verified):
//   A/B: row|col = lane&31, k = (lane>>5)*8 + e
//   C/D: col = lane&31, row = (reg&3) + 8*(reg>>2) + 4*(lane>>5)
// ---------------------------------------------------------------------------
__global__ __launch_bounds__(256) void attn_kernel(
    const unsigned short* __restrict__ qbuf, const unsigned short* __restrict__ kbuf,
    const unsigned short* __restrict__ vtbuf, unsigned short* __restrict__ obuf)
{
    __shared__ __align__(16) unsigned short sK[3][64 * 64];  // [kv][d], swizzled
    __shared__ __align__(16) unsigned short sV[3][64 * 64];  // [d][kv], swizzled

    const int tid  = threadIdx.x;
    const int wid  = tid >> 6;
    const int lane = tid & 63;
    const int hi   = lane >> 5;          // 0/1: which half-row of the q pair
    const int q5   = lane & 31;          // q column within wave tile

    const int x  = blockIdx.x;           // [0,512)
    const int s  = 15 - (x >> 5);        // q-super (128 rows), heavy first
    const int bh = x & 31;               // all blocks of bh land on XCD bh%8
    const int b  = bh >> 4, h = bh & 15;

    const unsigned short* Qh = qbuf  + (size_t)bh * S_LEN * HDIM;
    const unsigned short* Kh = kbuf  + (size_t)bh * S_LEN * HDIM;
    const unsigned short* Vt = vtbuf + (size_t)bh * HDIM * S_LEN;

    const int diag  = 2 * s + (wid >> 1);   // this wave's diagonal kv tile
    const int T     = 2 * s + 2;            // kv tiles staged by the block
    const int qrow0 = 128 * s + 32 * wid;
    const int qg    = qrow0 + q5;           // this lane-pair's q row

    // co-stage K tile (waves 0,1) + V^T tile (waves 2,3); 4 chunks/lane.
    // Pre-swizzled global source, linear LDS dest (rule #21).
    auto stage = [&](int t, int buf) {
#pragma unroll
        for (int i = 0; i < 4; ++i) {
            if (wid < 2) {
                int cidx = wid * 256 + i * 64 + lane;
                int row = cidx >> 3, col = ((cidx & 7) ^ (row & 7)) << 3;
                load_lds16(Kh + (size_t)(t * 64 + row) * HDIM + col,
                           &sK[buf][(wid * 256 + i * 64) * 8]);
            } else {
                int cidx = (wid - 2) * 256 + i * 64 + lane;
                int row = cidx >> 3, col = ((cidx & 7) ^ (row & 7)) << 3;
                load_lds16(Vt + (size_t)row * S_LEN + t * 64 + col,
                           &sV[buf][((wid - 2) * 256 + i * 64) * 8]);
            }
        }
    };

    // Q B-fragments (pre-scaled by 0.125*log2e): col=q5, k=ks*16+hi*8+e
    bf16x8 aq[4];
#pragma unroll
    for (int ks = 0; ks < 4; ++ks)
        aq[ks] = *(const bf16x8*)&Qh[(size_t)qg * HDIM + ks * 16 + hi * 8];

    f32x16 o2[2] = {};               // O[d=32*t2+(r&3)+4hi+8(r>>2)][q]
    float m_i = -1e30f, l_i = 0.f;   // per-lane partial l (pair-combined at end)

    stage(0, 0);
    stage(1, 1);

    for (int t = 0; t < T; ++t) {
        const int buf = t % 3;
        // counted wait: tile t landed (own 4 loads), t+1 still in flight
        asm volatile("s_waitcnt vmcnt(4)" ::: "memory");
        __builtin_amdgcn_s_barrier();
        stage(t + 2 < T ? t + 2 : t, (t + 2) % 3);   // clamp -> distinct buf

        if (t <= diag) {
            // swapped QK^T: acc[t2] = D[kv = t2*32 + rowfmt(r,hi)][q = q5]
            f32x16 acc[2] = {};
            __builtin_amdgcn_s_setprio(1);
#pragma unroll
            for (int ks = 0; ks < 4; ++ks) {
                bf16x8 k0 = *(const bf16x8*)&sK[buf][swz(q5,      ks * 16 + hi * 8)];
                bf16x8 k1 = *(const bf16x8*)&sK[buf][swz(q5 + 32, ks * 16 + hi * 8)];
                acc[0] = __builtin_amdgcn_mfma_f32_32x32x16_bf16(k0, aq[ks], acc[0], 0, 0, 0);
                acc[1] = __builtin_amdgcn_mfma_f32_32x32x16_bf16(k1, aq[ks], acc[1], 0, 0, 0);
            }
            __builtin_amdgcn_s_setprio(0);

            // causal mask (diagonal tile only): kv = t*64+t2*32+(r&3)+4hi+8(r>>2)
            if (t == diag) {
#pragma unroll
                for (int t2 = 0; t2 < 2; ++t2) {
                    int base = t * 64 + t2 * 32 + 4 * hi;
#pragma unroll
                    for (int r = 0; r < 16; ++r)
                        if (base + (r & 3) + 8 * (r >> 2) > qg) acc[t2][r] = -1e30f;
                }
            }

            // in-lane max over 32 values (tree); cross-lane only in rare branch
            float mx[8];
#pragma unroll
            for (int i = 0; i < 8; ++i)
                mx[i] = fmaxf(fmaxf(acc[i >> 2][(i & 3) * 4 + 0], acc[i >> 2][(i & 3) * 4 + 1]),
                              fmaxf(acc[i >> 2][(i & 3) * 4 + 2], acc[i >> 2][(i & 3) * 4 + 3]));
            float pm = fmaxf(fmaxf(fmaxf(mx[0], mx[1]), fmaxf(mx[2], mx[3])),
                             fmaxf(fmaxf(mx[4], mx[5]), fmaxf(mx[6], mx[7])));

            // defer-rescale (T13): wave-uniform trigger keeps m_i pair-consistent
            if (__any(pm > m_i + 8.0f)) {
                float pmr   = fmaxf(pm, __shfl_xor(pm, 32, 64));
                float m_new = fmaxf(m_i, pmr);
                float fac, dm = m_i - m_new;
                asm("v_exp_f32 %0, %1" : "=v"(fac) : "v"(dm));   // exp2 domain
                l_i *= fac;
                m_i  = m_new;
#pragma unroll
                for (int t2 = 0; t2 < 2; ++t2)
#pragma unroll
                    for (int r = 0; r < 16; ++r) o2[t2][r] *= fac;
            }

            // P = exp2(S - m_i); pack bf16 pairs in-register; per-lane sum
            unsigned pd[2][8];
            float lsum = 0.f;
#pragma unroll
            for (int t2 = 0; t2 < 2; ++t2) {
                float ev[16];
#pragma unroll
                for (int r = 0; r < 16; ++r) {
                    float a = acc[t2][r] - m_i;
                    asm("v_exp_f32 %0, %1" : "=v"(ev[r]) : "v"(a));
                }
                float s4[4];
#pragma unroll
                for (int u = 0; u < 4; ++u) {
                    s4[u] = (ev[4 * u] + ev[4 * u + 1]) + (ev[4 * u + 2] + ev[4 * u + 3]);
                    pd[t2][2 * u]     = pkbf(ev[4 * u],     ev[4 * u + 1]);
                    pd[t2][2 * u + 1] = pkbf(ev[4 * u + 2], ev[4 * u + 3]);
                }
                lsum += (s4[0] + s4[1]) + (s4[2] + s4[3]);
            }
            l_i += lsum;

            // PV: B-frag P[kv=ks*16+hi*8+e][q] built via pair exchange:
            //  hi=0 frag = [pd0, pd1, sx(pd0), sx(pd1)]   (kv 0-7 of window)
            //  hi=1 frag = [sx(pd2), sx(pd3), pd2, pd3]   (kv 8-15 of window)
            __builtin_amdgcn_s_setprio(1);
#pragma unroll
            for (int ks = 0; ks < 4; ++ks) {
                const int t2 = ks >> 1, k1 = ks & 1;
                unsigned p0 = pd[t2][4 * k1 + 0], p1 = pd[t2][4 * k1 + 1];
                unsigned p2 = pd[t2][4 * k1 + 2], p3 = pd[t2][4 * k1 + 3];
                unsigned s0 = __shfl_xor(p0, 32, 64), s1 = __shfl_xor(p1, 32, 64);
                unsigned s2 = __shfl_xor(p2, 32, 64), s3 = __shfl_xor(p3, 32, 64);
                u32x4 fw;
                fw[0] = hi ? s2 : p0;
                fw[1] = hi ? s3 : p1;
                fw[2] = hi ? p2 : s0;
                fw[3] = hi ? p3 : s1;
                bf16x8 pf = __builtin_bit_cast(bf16x8, fw);
                bf16x8 v0 = *(const bf16x8*)&sV[buf][swz(q5,      ks * 16 + hi * 8)];
                bf16x8 v1 = *(const bf16x8*)&sV[buf][swz(q5 + 32, ks * 16 + hi * 8)];
                o2[0] = __builtin_amdgcn_mfma_f32_32x32x16_bf16(v0, pf, o2[0], 0, 0, 0);
                o2[1] = __builtin_amdgcn_mfma_f32_32x32x16_bf16(v1, pf, o2[1], 0, 0, 0);
            }
            __builtin_amdgcn_s_setprio(0);
        }
        // no trailing drain: next iteration's vmcnt(4)+barrier gates reuse
    }

    // drain in-flight clamped tail prefetches before endpgm (R5 lesson)
    asm volatile("s_waitcnt vmcnt(0)" ::: "memory");

    // epilogue: combine the hi-pair's l partials once; 8x 8B stores per lane
    float l_full = l_i + __shfl_xor(l_i, 32, 64);
    float rl = 1.0f / l_full;
    unsigned short* orow = &obuf[((size_t)(b * S_LEN + qg)) * EMBD + h * HDIM];
#pragma unroll
    for (int t2 = 0; t2 < 2; ++t2)
#pragma unroll
        for (int u = 0; u < 4; ++u) {
            uint2 pw;
            pw.x = pkbf(o2[t2][4 * u] * rl,     o2[t2][4 * u + 1] * rl);
            pw.y = pkbf(o2[t2][4 * u + 2] * rl, o2[t2][4 * u + 3] * rl);
            *(uint2*)&orow[t2 * 32 + 4 * hi + 8 * u] = pw;
        }
}

extern "C" void kernel_launch(void* const* d_in, const int* in_sizes, int n_in,
                              void* d_out, int out_size, void* d_ws, size_t ws_size,
                              hipStream_t stream) {
    const float* hidden = (const float*)d_in[0];  // [2,2048,1024]
    const float* w_attn = (const float*)d_in[1];  // [3072,1024]
    const float* b_attn = (const float*)d_in[2];  // [3072]
    const float* w_proj = (const float*)d_in[3];  // [1024,1024]
    const float* b_proj = (const float*)d_in[4];  // [1024]
    float* out = (float*)d_out;                   // [2,2048,1024] fp32

    unsigned short* Xbf  = (unsigned short*)d_ws;          // 4096*1024
    unsigned short* Wabf = Xbf  + (size_t)ROWS * EMBD;     // 3072*1024
    unsigned short* Wpbf = Wabf + (size_t)3 * EMBD * EMBD; // 1024*1024
    unsigned short* qb   = Wpbf + (size_t)EMBD * EMBD;     // [B,H,S,D] (q pre-scaled)
    unsigned short* kb   = qb + (size_t)BATCHN * NHEAD * S_LEN * HDIM;
    unsigned short* vtb  = kb + (size_t)BATCHN * NHEAD * S_LEN * HDIM; // [B,H,D,S]
    unsigned short* ob   = vtb + (size_t)BATCHN * NHEAD * S_LEN * HDIM; // [B,S,E]

    // fp32 -> bf16 converts (single launch; dsts contiguous in ws)
    const int n0   = ROWS * EMBD;
    const int n01  = n0 + 3 * EMBD * EMBD;
    const int ntot = n01 + EMBD * EMBD;
    cvt3_f32_bf16<<<2048, 256, 0, stream>>>(hidden, w_attn, w_proj, Xbf,
                                            n0, n01, ntot);

    // QKV projection: q (pre-scaled), k, V^T
    gemm_bt<1><<<dim3(ROWS / 128, 3 * EMBD / 128), 256, 0, stream>>>(
        Xbf, Wabf, b_attn, nullptr, qb, kb, vtb, ROWS, 3 * EMBD, EMBD);

    // causal attention: 512 blocks, 4 waves, 32x32 MFMA, LPT-ordered
    attn_kernel<<<dim3(512), 256, 0, stream>>>(qb, kb, vtb, ob);

    // output projection -> fp32 out
    gemm_bt<0><<<dim3(ROWS / 128, EMBD / 128), 256, 0, stream>>>(
        ob, Wpbf, b_proj, out, nullptr, nullptr, nullptr, ROWS, EMBD, EMBD);
}

// Round 10
// 122.795 us; speedup vs baseline: 1.3869x; 1.1437x over previous
//
#include <hip/hip_runtime.h>
#include <stdint.h>

// Problem constants (GPT-2 attention block)
#define S_LEN  2048
#define EMBD   1024
#define NHEAD  16
#define HDIM   64
#define BATCHN 2
#define ROWS   (BATCHN * S_LEN)   // 4096 = flattened B*S

using bf16x8 = __attribute__((ext_vector_type(8))) __bf16;
using f32x4  = __attribute__((ext_vector_type(4))) float;
using f32x16 = __attribute__((ext_vector_type(16))) float;
using u32x4  = __attribute__((ext_vector_type(4))) unsigned;

typedef const __attribute__((address_space(1))) void* gas_ptr;
typedef __attribute__((address_space(3)))       void* las_ptr;

// Async global->LDS, 16B per lane. LDS dest = wave-uniform base + lane*16.
__device__ __forceinline__ void load_lds16(const void* g, void* l) {
    __builtin_amdgcn_global_load_lds((gas_ptr)(uintptr_t)g, (las_ptr)(uintptr_t)l, 16, 0, 0);
}

// fp32 -> bf16 round-to-nearest-even
__device__ __forceinline__ unsigned short f2bf(float f) {
    unsigned u = __builtin_bit_cast(unsigned, f);
    u += 0x7fffu + ((u >> 16) & 1u);
    return (unsigned short)(u >> 16);
}

// pack 2 floats -> 1 dword of 2 bf16 (lo = a, hi = b); hw cvt_pk (no builtin)
__device__ __forceinline__ unsigned pkbf(float a, float b) {
    unsigned r;
    asm("v_cvt_pk_bf16_f32 %0, %1, %2" : "=v"(r) : "v"(a), "v"(b));
    return r;
}

// XOR-swizzled element offset within a [R][64] bf16 tile (16B-chunk XOR row&7).
// Fixes the 16-way ds_read_b128 bank conflict of 128B-stride rows (T2).
__device__ __forceinline__ int swz(int row, int ebase) {
    int byte = (row << 7) + (ebase << 1);
    byte ^= (row & 7) << 4;
    return byte >> 1;
}

// Merged fp32->bf16 convert for 3 sources; destinations are contiguous in ws.
__global__ void cvt3_f32_bf16(const float* __restrict__ s0,
                              const float* __restrict__ s1,
                              const float* __restrict__ s2,
                              unsigned short* __restrict__ d,
                              int n0, int n01, int ntot) {
    int i = blockIdx.x * blockDim.x + threadIdx.x;
    int stride = gridDim.x * blockDim.x;
    for (int idx = i * 4; idx < ntot; idx += stride * 4) {
        const float* s; int off;
        if (idx < n0)       { s = s0; off = idx; }
        else if (idx < n01) { s = s1; off = idx - n0; }
        else                { s = s2; off = idx - n01; }
        float4 f = *(const float4*)(s + off);
        uint2 p;
        p.x = (unsigned)f2bf(f.x) | ((unsigned)f2bf(f.y) << 16);
        p.y = (unsigned)f2bf(f.z) | ((unsigned)f2bf(f.w) << 16);
        *(uint2*)(d + idx) = p;
    }
}

// ---------------------------------------------------------------------------
// bf16 GEMM, C[m][n] = sum_k A[m][k]*B[n][k] (+bias[n]).  A:[M][K] B:[N][K]
// 128x128 tile, BK=64, 4 waves (2x2), each wave 64x64 via 16x16x32 MFMA.
// LDS tiles XOR-swizzled (T2): pre-swizzled global source + swz() reads —
// R9 counters showed 9.4e6 conflict-cycles/dispatch (16-way on ds_read_b128).
// MODE 0: write fp32 C[m*N+n] (+bias)                 (output projection)
// MODE 1: scatter bf16 q(pre-scaled)/k [B,H,S,D], V^T [B,H,D,S]  (QKV)
// ---------------------------------------------------------------------------
#define SCALE_Q 0.18033688011112042f   // 0.125 * log2(e): softmax in exp2 domain

template <int MODE>
__global__ __launch_bounds__(256) void gemm_bt(
    const unsigned short* __restrict__ A, const unsigned short* __restrict__ B,
    const float* __restrict__ bias, float* __restrict__ Cout,
    unsigned short* __restrict__ qb, unsigned short* __restrict__ kb,
    unsigned short* __restrict__ vb, int M, int N, int K)
{
    __shared__ __align__(16) unsigned short sA[128 * 64];
    __shared__ __align__(16) unsigned short sB[128 * 64];

    const int tid  = threadIdx.x;
    const int wid  = tid >> 6;
    const int lane = tid & 63;
    const int g    = lane >> 4;       // 0..3
    const int c    = lane & 15;       // 0..15
    const int bm   = blockIdx.x * 128;
    const int bn   = blockIdx.y * 128;
    const int wm   = (wid >> 1) * 64;
    const int wn   = (wid & 1) * 64;

    f32x4 acc[4][4] = {};

    for (int k0 = 0; k0 < K; k0 += 64) {
        // stage: pre-swizzled global source, linear LDS dest (rule #21)
#pragma unroll
        for (int i = 0; i < 4; ++i) {
            int cidx = i * 256 + tid;            // 16B chunk index in tile
            int row  = cidx >> 3;
            int col  = ((cidx & 7) ^ (row & 7)) << 3;
            load_lds16(A + (size_t)(bm + row) * K + k0 + col,
                       &sA[i * 2048 + wid * 512]);
            load_lds16(B + (size_t)(bn + row) * K + k0 + col,
                       &sB[i * 2048 + wid * 512]);
        }
        __syncthreads();
#pragma unroll
        for (int kk = 0; kk < 2; ++kk) {
            bf16x8 af[4], bfr[4];
#pragma unroll
            for (int i = 0; i < 4; ++i)
                af[i] = *(const bf16x8*)&sA[swz(wm + i * 16 + c, kk * 32 + g * 8)];
#pragma unroll
            for (int j = 0; j < 4; ++j)
                bfr[j] = *(const bf16x8*)&sB[swz(wn + j * 16 + c, kk * 32 + g * 8)];
#pragma unroll
            for (int i = 0; i < 4; ++i)
#pragma unroll
                for (int j = 0; j < 4; ++j)
                    acc[i][j] = __builtin_amdgcn_mfma_f32_16x16x32_bf16(
                        af[i], bfr[j], acc[i][j], 0, 0, 0);
        }
        __syncthreads();
    }

#pragma unroll
    for (int i = 0; i < 4; ++i)
#pragma unroll
        for (int j = 0; j < 4; ++j) {
            int n = bn + wn + j * 16 + c;
            float bv = bias[n];
            if (MODE == 0) {
#pragma unroll
                for (int r = 0; r < 4; ++r) {
                    int m = bm + wm + i * 16 + g * 4 + r;
                    Cout[(size_t)m * N + n] = acc[i][j][r] + bv;
                }
            } else {
                int which = n >> 10, h = (n & 1023) >> 6, d = n & 63;
                if (which < 2) {
                    unsigned short* dst = (which == 0) ? qb : kb;
                    float sc = (which == 0) ? SCALE_Q : 1.0f;
#pragma unroll
                    for (int r = 0; r < 4; ++r) {
                        int m = bm + wm + i * 16 + g * 4 + r;
                        int b = m >> 11, s = m & 2047;
                        dst[(((size_t)b * NHEAD + h) * S_LEN + s) * HDIM + d] =
                            f2bf((acc[i][j][r] + bv) * sc);
                    }
                } else {
                    // V^T [B,H,D,S]: pack 4 consecutive s into one 8B store
                    int m0 = bm + wm + i * 16 + g * 4;
                    int b = m0 >> 11, s0 = m0 & 2047;
                    uint2 p;
                    p.x = pkbf(acc[i][j][0] + bv, acc[i][j][1] + bv);
                    p.y = pkbf(acc[i][j][2] + bv, acc[i][j][3] + bv);
                    *(uint2*)&vb[(((size_t)b * NHEAD + h) * HDIM + d) * S_LEN + s0] = p;
                }
            }
        }
}

// ---------------------------------------------------------------------------
// Flash-style causal attention — 32x32 MFMA structure (m214-class).
// Grid: 512 blocks x 256 thr (4 waves). Wave owns 32 q-rows; block = 128.
// Balanced pairing: s = x<256 ? 15-(x>>5) : (x>>5)-8 — under round-robin
// dispatch CU i gets blocks x and x+256 with s summing to 15 => exactly 34
// kv tiles per CU (R9's LPT gave 20-48). Heavy supers dispatch first.
// bh = x&31 -> XCD = bh%8 (K/V L2 locality).
// Swapped QK^T (D[kv][q=lane&31]); q-row owned by a hi-lane pair (lane^32).
// K and V^T co-staged into swizzled LDS (3-buffer, counted vmcnt(4), one
// barrier/tile). P stays IN REGISTERS: cvt_pk pairs + 4 shfl_xor(32) + hi-
// selects per 16-kv slice build the PV B-fragment (no LDS round-trip).
// 32x32x16 layouts (m74/m101/m89-verified):
//   A/B: row|col = lane&31, k = (lane>>5)*8 + e
//   C/D: col = lane&31, row = (reg&3) + 8*(reg>>2) + 4*(lane>>5)
// ---------------------------------------------------------------------------
__global__ __launch_bounds__(256) void attn_kernel(
    const unsigned short* __restrict__ qbuf, const unsigned short* __restrict__ kbuf,
    const unsigned short* __restrict__ vtbuf, unsigned short* __restrict__ obuf)
{
    __shared__ __align__(16) unsigned short sK[3][64 * 64];  // [kv][d], swizzled
    __shared__ __align__(16) unsigned short sV[3][64 * 64];  // [d][kv], swizzled

    const int tid  = threadIdx.x;
    const int wid  = tid >> 6;
    const int lane = tid & 63;
    const int hi   = lane >> 5;          // 0/1: which half-row of the q pair
    const int q5   = lane & 31;          // q column within wave tile

    const int x  = blockIdx.x;           // [0,512)
    const int s  = (x < 256) ? (15 - (x >> 5)) : ((x >> 5) - 8);
    const int bh = x & 31;               // all blocks of bh land on XCD bh%8
    const int b  = bh >> 4, h = bh & 15;

    const unsigned short* Qh = qbuf  + (size_t)bh * S_LEN * HDIM;
    const unsigned short* Kh = kbuf  + (size_t)bh * S_LEN * HDIM;
    const unsigned short* Vt = vtbuf + (size_t)bh * HDIM * S_LEN;

    const int diag  = 2 * s + (wid >> 1);   // this wave's diagonal kv tile
    const int T     = 2 * s + 2;            // kv tiles staged by the block
    const int qrow0 = 128 * s + 32 * wid;
    const int qg    = qrow0 + q5;           // this lane-pair's q row

    // co-stage K tile (waves 0,1) + V^T tile (waves 2,3); 4 chunks/lane.
    // Pre-swizzled global source, linear LDS dest (rule #21).
    auto stage = [&](int t, int buf) {
#pragma unroll
        for (int i = 0; i < 4; ++i) {
            if (wid < 2) {
                int cidx = wid * 256 + i * 64 + lane;
                int row = cidx >> 3, col = ((cidx & 7) ^ (row & 7)) << 3;
                load_lds16(Kh + (size_t)(t * 64 + row) * HDIM + col,
                           &sK[buf][(wid * 256 + i * 64) * 8]);
            } else {
                int cidx = (wid - 2) * 256 + i * 64 + lane;
                int row = cidx >> 3, col = ((cidx & 7) ^ (row & 7)) << 3;
                load_lds16(Vt + (size_t)row * S_LEN + t * 64 + col,
                           &sV[buf][((wid - 2) * 256 + i * 64) * 8]);
            }
        }
    };

    // Q B-fragments (pre-scaled by 0.125*log2e): col=q5, k=ks*16+hi*8+e
    bf16x8 aq[4];
#pragma unroll
    for (int ks = 0; ks < 4; ++ks)
        aq[ks] = *(const bf16x8*)&Qh[(size_t)qg * HDIM + ks * 16 + hi * 8];

    f32x16 o2[2] = {};               // O[d=32*t2+(r&3)+4hi+8(r>>2)][q]
    float m_i = -1e30f, l_i = 0.f;   // per-lane partial l (pair-combined at end)

    stage(0, 0);
    stage(1, 1);

    for (int t = 0; t < T; ++t) {
        const int buf = t % 3;
        // counted wait: tile t landed (own 4 loads), t+1 still in flight
        asm volatile("s_waitcnt vmcnt(4)" ::: "memory");
        __builtin_amdgcn_s_barrier();
        stage(t + 2 < T ? t + 2 : t, (t + 2) % 3);   // clamp -> distinct buf

        if (t <= diag) {
            // swapped QK^T: acc[t2] = D[kv = t2*32 + rowfmt(r,hi)][q = q5]
            f32x16 acc[2] = {};
            __builtin_amdgcn_s_setprio(1);
#pragma unroll
            for (int ks = 0; ks < 4; ++ks) {
                bf16x8 k0 = *(const bf16x8*)&sK[buf][swz(q5,      ks * 16 + hi * 8)];
                bf16x8 k1 = *(const bf16x8*)&sK[buf][swz(q5 + 32, ks * 16 + hi * 8)];
                acc[0] = __builtin_amdgcn_mfma_f32_32x32x16_bf16(k0, aq[ks], acc[0], 0, 0, 0);
                acc[1] = __builtin_amdgcn_mfma_f32_32x32x16_bf16(k1, aq[ks], acc[1], 0, 0, 0);
            }
            __builtin_amdgcn_s_setprio(0);

            // causal mask (diagonal tile only): kv = t*64+t2*32+(r&3)+4hi+8(r>>2)
            if (t == diag) {
#pragma unroll
                for (int t2 = 0; t2 < 2; ++t2) {
                    int base = t * 64 + t2 * 32 + 4 * hi;
#pragma unroll
                    for (int r = 0; r < 16; ++r)
                        if (base + (r & 3) + 8 * (r >> 2) > qg) acc[t2][r] = -1e30f;
                }
            }

            // in-lane max over 32 values (tree); cross-lane only in rare branch
            float mx[8];
#pragma unroll
            for (int i = 0; i < 8; ++i)
                mx[i] = fmaxf(fmaxf(acc[i >> 2][(i & 3) * 4 + 0], acc[i >> 2][(i & 3) * 4 + 1]),
                              fmaxf(acc[i >> 2][(i & 3) * 4 + 2], acc[i >> 2][(i & 3) * 4 + 3]));
            float pm = fmaxf(fmaxf(fmaxf(mx[0], mx[1]), fmaxf(mx[2], mx[3])),
                             fmaxf(fmaxf(mx[4], mx[5]), fmaxf(mx[6], mx[7])));

            // defer-rescale (T13): wave-uniform trigger keeps m_i pair-consistent
            if (__any(pm > m_i + 8.0f)) {
                float pmr   = fmaxf(pm, __shfl_xor(pm, 32, 64));
                float m_new = fmaxf(m_i, pmr);
                float fac, dm = m_i - m_new;
                asm("v_exp_f32 %0, %1" : "=v"(fac) : "v"(dm));   // exp2 domain
                l_i *= fac;
                m_i  = m_new;
#pragma unroll
                for (int t2 = 0; t2 < 2; ++t2)
#pragma unroll
                    for (int r = 0; r < 16; ++r) o2[t2][r] *= fac;
            }

            // P = exp2(S - m_i); pack bf16 pairs in-register; per-lane sum
            unsigned pd[2][8];
            float lsum = 0.f;
#pragma unroll
            for (int t2 = 0; t2 < 2; ++t2) {
                float ev[16];
#pragma unroll
                for (int r = 0; r < 16; ++r) {
                    float a = acc[t2][r] - m_i;
                    asm("v_exp_f32 %0, %1" : "=v"(ev[r]) : "v"(a));
                }
                float s4[4];
#pragma unroll
                for (int u = 0; u < 4; ++u) {
                    s4[u] = (ev[4 * u] + ev[4 * u + 1]) + (ev[4 * u + 2] + ev[4 * u + 3]);
                    pd[t2][2 * u]     = pkbf(ev[4 * u],     ev[4 * u + 1]);
                    pd[t2][2 * u + 1] = pkbf(ev[4 * u + 2], ev[4 * u + 3]);
                }
                lsum += (s4[0] + s4[1]) + (s4[2] + s4[3]);
            }
            l_i += lsum;

            // PV: B-frag P[kv=ks*16+hi*8+e][q] built via pair exchange:
            //  hi=0 frag = [pd0, pd1, sx(pd0), sx(pd1)]   (kv 0-7 of window)
            //  hi=1 frag = [sx(pd2), sx(pd3), pd2, pd3]   (kv 8-15 of window)
            __builtin_amdgcn_s_setprio(1);
#pragma unroll
            for (int ks = 0; ks < 4; ++ks) {
                const int t2 = ks >> 1, k1 = ks & 1;
                unsigned p0 = pd[t2][4 * k1 + 0], p1 = pd[t2][4 * k1 + 1];
                unsigned p2 = pd[t2][4 * k1 + 2], p3 = pd[t2][4 * k1 + 3];
                unsigned s0 = __shfl_xor(p0, 32, 64), s1 = __shfl_xor(p1, 32, 64);
                unsigned s2 = __shfl_xor(p2, 32, 64), s3 = __shfl_xor(p3, 32, 64);
                u32x4 fw;
                fw[0] = hi ? s2 : p0;
                fw[1] = hi ? s3 : p1;
                fw[2] = hi ? p2 : s0;
                fw[3] = hi ? p3 : s1;
                bf16x8 pf = __builtin_bit_cast(bf16x8, fw);
                bf16x8 v0 = *(const bf16x8*)&sV[buf][swz(q5,      ks * 16 + hi * 8)];
                bf16x8 v1 = *(const bf16x8*)&sV[buf][swz(q5 + 32, ks * 16 + hi * 8)];
                o2[0] = __builtin_amdgcn_mfma_f32_32x32x16_bf16(v0, pf, o2[0], 0, 0, 0);
                o2[1] = __builtin_amdgcn_mfma_f32_32x32x16_bf16(v1, pf, o2[1], 0, 0, 0);
            }
            __builtin_amdgcn_s_setprio(0);
        }
        // no trailing drain: next iteration's vmcnt(4)+barrier gates reuse
    }

    // drain in-flight clamped tail prefetches before endpgm (R5 lesson)
    asm volatile("s_waitcnt vmcnt(0)" ::: "memory");

    // epilogue: combine the hi-pair's l partials once; 8x 8B stores per lane
    float l_full = l_i + __shfl_xor(l_i, 32, 64);
    float rl = 1.0f / l_full;
    unsigned short* orow = &obuf[((size_t)(b * S_LEN + qg)) * EMBD + h * HDIM];
#pragma unroll
    for (int t2 = 0; t2 < 2; ++t2)
#pragma unroll
        for (int u = 0; u < 4; ++u) {
            uint2 pw;
            pw.x = pkbf(o2[t2][4 * u] * rl,     o2[t2][4 * u + 1] * rl);
            pw.y = pkbf(o2[t2][4 * u + 2] * rl, o2[t2][4 * u + 3] * rl);
            *(uint2*)&orow[t2 * 32 + 4 * hi + 8 * u] = pw;
        }
}

extern "C" void kernel_launch(void* const* d_in, const int* in_sizes, int n_in,
                              void* d_out, int out_size, void* d_ws, size_t ws_size,
                              hipStream_t stream) {
    const float* hidden = (const float*)d_in[0];  // [2,2048,1024]
    const float* w_attn = (const float*)d_in[1];  // [3072,1024]
    const float* b_attn = (const float*)d_in[2];  // [3072]
    const float* w_proj = (const float*)d_in[3];  // [1024,1024]
    const float* b_proj = (const float*)d_in[4];  // [1024]
    float* out = (float*)d_out;                   // [2,2048,1024] fp32

    unsigned short* Xbf  = (unsigned short*)d_ws;          // 4096*1024
    unsigned short* Wabf = Xbf  + (size_t)ROWS * EMBD;     // 3072*1024
    unsigned short* Wpbf = Wabf + (size_t)3 * EMBD * EMBD; // 1024*1024
    unsigned short* qb   = Wpbf + (size_t)EMBD * EMBD;     // [B,H,S,D] (q pre-scaled)
    unsigned short* kb   = qb + (size_t)BATCHN * NHEAD * S_LEN * HDIM;
    unsigned short* vtb  = kb + (size_t)BATCHN * NHEAD * S_LEN * HDIM; // [B,H,D,S]
    unsigned short* ob   = vtb + (size_t)BATCHN * NHEAD * S_LEN * HDIM; // [B,S,E]

    // fp32 -> bf16 converts (single launch; dsts contiguous in ws)
    const int n0   = ROWS * EMBD;
    const int n01  = n0 + 3 * EMBD * EMBD;
    const int ntot = n01 + EMBD * EMBD;
    cvt3_f32_bf16<<<2048, 256, 0, stream>>>(hidden, w_attn, w_proj, Xbf,
                                            n0, n01, ntot);

    // QKV projection: q (pre-scaled), k, V^T
    gemm_bt<1><<<dim3(ROWS / 128, 3 * EMBD / 128), 256, 0, stream>>>(
        Xbf, Wabf, b_attn, nullptr, qb, kb, vtb, ROWS, 3 * EMBD, EMBD);

    // causal attention: 512 blocks, 4 waves, 32x32 MFMA, CU-balanced pairs
    attn_kernel<<<dim3(512), 256, 0, stream>>>(qb, kb, vtb, ob);

    // output projection -> fp32 out
    gemm_bt<0><<<dim3(ROWS / 128, EMBD / 128), 256, 0, stream>>>(
        ob, Wpbf, b_proj, out, nullptr, nullptr, nullptr, ROWS, EMBD, EMBD);
}